// Round 1
// baseline (1129.531 us; speedup 1.0000x reference)
//
#include <hip/hip_runtime.h>
#include <hip/hip_bf16.h>

// WeisfeilerLehman: labels0 = argmax(x, -1); 3x ordered polynomial hash over edges.
// All arithmetic mod 2^32 (uint32 wrap) == reference int64 truncated to int32.

#define WL_D 128

__global__ void wl_argmax(const float* __restrict__ x, unsigned* __restrict__ lab0, int n) {
    int wave = (int)((blockIdx.x * blockDim.x + threadIdx.x) >> 6);
    int lane = threadIdx.x & 63;
    if (wave >= n) return;
    const float* xr = x + (size_t)wave * WL_D;
    float v0 = xr[lane];
    float v1 = xr[lane + 64];
    float bv; int bi;
    if (v1 > v0) { bv = v1; bi = lane + 64; } else { bv = v0; bi = lane; }
    #pragma unroll
    for (int off = 32; off > 0; off >>= 1) {
        float ov = __shfl_down(bv, off, 64);
        int   oi = __shfl_down(bi, off, 64);
        if (ov > bv || (ov == bv && oi < bi)) { bv = ov; bi = oi; }
    }
    if (lane == 0) lab0[wave] = (unsigned)bi;
}

__global__ void wl_deg(const int* __restrict__ ei, unsigned* __restrict__ deg, int E) {
    int e = blockIdx.x * blockDim.x + threadIdx.x;
    if (e >= E) return;
    atomicAdd(&deg[ei[e]], 1u);
}

// Exclusive scan, two-level. scan1: per-block (512) exclusive scan + block sums.
__global__ void wl_scan1(const unsigned* __restrict__ in, unsigned* __restrict__ out,
                         unsigned* __restrict__ bsums, int n) {
    __shared__ unsigned tmp[512];
    int i = blockIdx.x * 512 + threadIdx.x;
    unsigned v = (i < n) ? in[i] : 0u;
    tmp[threadIdx.x] = v;
    __syncthreads();
    for (int off = 1; off < 512; off <<= 1) {
        unsigned t = (threadIdx.x >= (unsigned)off) ? tmp[threadIdx.x - off] : 0u;
        __syncthreads();
        tmp[threadIdx.x] += t;
        __syncthreads();
    }
    if (i < n) out[i] = tmp[threadIdx.x] - v;   // exclusive
    if (threadIdx.x == 511) bsums[blockIdx.x] = tmp[511];
}

// scan2: single block exclusive scan of block sums (nb <= 1024)
__global__ void wl_scan2(unsigned* __restrict__ bsums, int nb) {
    __shared__ unsigned tmp[1024];
    int t = threadIdx.x;
    unsigned v = (t < nb) ? bsums[t] : 0u;
    tmp[t] = v;
    __syncthreads();
    for (int off = 1; off < 1024; off <<= 1) {
        unsigned s = (t >= off) ? tmp[t - off] : 0u;
        __syncthreads();
        tmp[t] += s;
        __syncthreads();
    }
    if (t < nb) bsums[t] = tmp[t] - v;          // exclusive
}

__global__ void wl_scan3(unsigned* __restrict__ out, const unsigned* __restrict__ bsums, int n) {
    int i = blockIdx.x * 512 + threadIdx.x;
    if (i < n) out[i] += bsums[blockIdx.x];
}

__global__ void wl_scatter(const int* __restrict__ ei, const unsigned* __restrict__ row_start,
                           unsigned* __restrict__ cursor, unsigned* __restrict__ csr_eid, int E) {
    int e = blockIdx.x * blockDim.x + threadIdx.x;
    if (e >= E) return;
    int r = ei[e];
    unsigned slot = atomicAdd(&cursor[r], 1u);
    csr_eid[row_start[r] + slot] = (unsigned)e;
}

// Per row: rank each edge id among the row's edges (edge ids unique), exp = d-1-rank,
// pow31[eid] = 31^exp mod 2^32.
__global__ void wl_rank_pow(const unsigned* __restrict__ row_start, const unsigned* __restrict__ deg,
                            const unsigned* __restrict__ csr_eid, unsigned* __restrict__ pw, int n) {
    int r = blockIdx.x * blockDim.x + threadIdx.x;
    if (r >= n) return;
    unsigned start = row_start[r];
    unsigned d = deg[r];
    for (unsigned j = 0; j < d; ++j) {
        unsigned ej = csr_eid[start + j];
        unsigned rank = 0;
        for (unsigned i = 0; i < d; ++i)
            rank += (csr_eid[start + i] < ej) ? 1u : 0u;
        unsigned ex = d - 1u - rank;
        unsigned p = 1u;
        for (unsigned t = 0; t < ex; ++t) p *= 31u;
        pw[ej] = p;
    }
}

__global__ void wl_propagate(const int* __restrict__ ei, const unsigned* __restrict__ pw,
                             const unsigned* __restrict__ lin, unsigned* __restrict__ lout, int E) {
    int e = blockIdx.x * blockDim.x + threadIdx.x;
    if (e >= E) return;
    int r = ei[e];
    int c = ei[E + e];
    unsigned v = lin[c] * pw[e];
    atomicAdd(&lout[r], v);   // wraps mod 2^32 — order-independent
}

__global__ void wl_write_out(const unsigned* __restrict__ l0, const unsigned* __restrict__ l1,
                             const unsigned* __restrict__ l2, const unsigned* __restrict__ l3,
                             int* __restrict__ out, int n) {
    int i = blockIdx.x * blockDim.x + threadIdx.x;
    if (i >= n) return;
    int a0 = (int)l0[i], a1 = (int)l1[i], a2 = (int)l2[i], a3 = (int)l3[i];
    out[i]         = a3;   // labels3 (final)
    out[n + i]     = a0;   // labels0
    out[2 * n + i] = a1;   // labels1
    out[3 * n + i] = a2;   // labels2
    out[4 * n + i] = a3;   // labels3
}

extern "C" void kernel_launch(void* const* d_in, const int* in_sizes, int n_in,
                              void* d_out, int out_size, void* d_ws, size_t ws_size,
                              hipStream_t stream) {
    const float* x  = (const float*)d_in[0];
    const int*   ei = (const int*)d_in[1];      // int inputs arrive as int32
    int* out = (int*)d_out;

    const int N = in_sizes[0] / WL_D;
    const int E = in_sizes[1] / 2;

    // workspace layout (uint32 units)
    unsigned* ws   = (unsigned*)d_ws;
    unsigned* lab0 = ws;               // N
    unsigned* lab1 = lab0 + N;         // N
    unsigned* lab2 = lab1 + N;         // N
    unsigned* lab3 = lab2 + N;         // N
    unsigned* deg  = lab3 + N;         // N
    unsigned* cur  = deg + N;          // N
    unsigned* rs   = cur + N;          // N   (row_start, exclusive scan of deg)
    unsigned* bs   = rs + N;           // 1024 (block sums)
    unsigned* csr  = bs + 1024;        // E   (edge ids grouped by row, unordered)
    unsigned* pw   = csr + E;          // E   (31^exp per edge)

    // zero: lab0..cur  (lab1-3 are atomic accumulators, deg/cur histograms)
    hipMemsetAsync(ws, 0, (size_t)6 * N * sizeof(unsigned), stream);

    const int BT = 256;
    int gridN  = (N + BT - 1) / BT;
    int gridE  = (E + BT - 1) / BT;
    int gridAM = (N + 3) / 4;                 // 4 waves per block, 1 wave/node
    int nb     = (N + 511) / 512;             // scan blocks (<=1024 supported)

    wl_argmax<<<gridAM, BT, 0, stream>>>(x, lab0, N);
    wl_deg<<<gridE, BT, 0, stream>>>(ei, deg, E);
    wl_scan1<<<nb, 512, 0, stream>>>(deg, rs, bs, N);
    wl_scan2<<<1, 1024, 0, stream>>>(bs, nb);
    wl_scan3<<<nb, 512, 0, stream>>>(rs, bs, N);
    wl_scatter<<<gridE, BT, 0, stream>>>(ei, rs, cur, csr, E);
    wl_rank_pow<<<gridN, BT, 0, stream>>>(rs, deg, csr, pw, N);

    wl_propagate<<<gridE, BT, 0, stream>>>(ei, pw, lab0, lab1, E);
    wl_propagate<<<gridE, BT, 0, stream>>>(ei, pw, lab1, lab2, E);
    wl_propagate<<<gridE, BT, 0, stream>>>(ei, pw, lab2, lab3, E);

    wl_write_out<<<gridN, BT, 0, stream>>>(lab0, lab1, lab2, lab3, out, N);
}